// Round 9
// baseline (446.608 us; speedup 1.0000x reference)
//
#include <hip/hip_runtime.h>
#include <hip/hip_bf16.h>

// Sizes (fixed by the reference): B=4096, D=1024, H1=2048, H2=1024, C=64, T=20
#define B_   4096
#define D_   1024
#define H1_  2048
#define H2_  1024
#define C_   64

typedef double d4 __attribute__((ext_vector_type(4)));

#if defined(__has_builtin)
#  if __has_builtin(__builtin_amdgcn_mfma_f64_16x16x4f64)
#    define MFMA64(A, B, C) __builtin_amdgcn_mfma_f64_16x16x4f64((A), (B), (C), 0, 0, 0)
#    define HAVE_MFMA64 1
#  elif __has_builtin(__builtin_amdgcn_mfma_f64_16x16x4_f64)
#    define MFMA64(A, B, C) __builtin_amdgcn_mfma_f64_16x16x4_f64((A), (B), (C), 0, 0, 0)
#    define HAVE_MFMA64 1
#  endif
#endif

// ---------------------------------------------------------------------------
// Probe: discover v_mfma_f64_16x16x4 D-fragment layout at runtime.
// ---------------------------------------------------------------------------
__global__ void k_probe(int* flag) {
#if defined(HAVE_MFMA64)
    int lane = threadIdx.x & 63;
    int lr = lane & 15, lk = lane >> 4;
    double a  = (double)(5 * lr + 3 * lk + 1);    // A[r][k] = 5r+3k+1
    double bb = (double)(11 * lk + 2 * lr + 2);   // B[k][c] = 11k+2c+2
    d4 c = {0.0, 0.0, 0.0, 0.0};
    c = MFMA64(a, bb, c);
    int okm[4] = {1, 1, 1, 1};
#pragma unroll
    for (int j = 0; j < 4; ++j) {
        double e1 = 0, e2 = 0, e3 = 0, e4 = 0;
        for (int k = 0; k < 4; ++k) {
            e1 += (double)(5 * (4 * lk + j) + 3 * k + 1) * (double)(11 * k + 2 * lr + 2);
            e2 += (double)(5 * lr + 3 * k + 1) * (double)(11 * k + 2 * (4 * lk + j) + 2);
            e3 += (double)(5 * (lk + 4 * j) + 3 * k + 1) * (double)(11 * k + 2 * lr + 2);
            e4 += (double)(5 * lr + 3 * k + 1) * (double)(11 * k + 2 * (lk + 4 * j) + 2);
        }
        if (c[j] != e1) okm[0] = 0;
        if (c[j] != e2) okm[1] = 0;
        if (c[j] != e3) okm[2] = 0;
        if (c[j] != e4) okm[3] = 0;
    }
    int f = 0;
    for (int m = 3; m >= 0; --m) {
        unsigned long long all = __ballot(okm[m] != 0);
        if (all == ~0ULL) f = m + 1;
    }
    if (lane == 0) flag[0] = f;
#else
    if ((threadIdx.x & 63) == 0) flag[0] = 0;
#endif
}

// ---------------------------------------------------------------------------
// Transpose: out[c][r] = in[r][c]   (f32, 32x32 LDS tiles)
// ---------------------------------------------------------------------------
__global__ __launch_bounds__(256) void k_transpose(const float* __restrict__ in,
                                                   float* __restrict__ out,
                                                   int R, int C) {
    __shared__ float t[32][33];
    int c0 = blockIdx.x * 32;
    int r0 = blockIdx.y * 32;
    int lx = threadIdx.x;
    int ly = threadIdx.y;
#pragma unroll
    for (int q = 0; q < 4; ++q) {
        int rr = ly + 8 * q;
        t[rr][lx] = in[(size_t)(r0 + rr) * C + (c0 + lx)];
    }
    __syncthreads();
#pragma unroll
    for (int q = 0; q < 4; ++q) {
        int cc = ly + 8 * q;
        out[(size_t)(c0 + cc) * R + (r0 + lx)] = t[lx][cc];
    }
}

// ---------------------------------------------------------------------------
// f64 MFMA GEMM v4: 128x128 tile, 512 thr, wave-tile 64x32.
// NEW vs v3:
//  - phase-exact pad: row k at 136k + 40*(k>>2) + 8*(k&3) + 8*((k>>1)&1).
//    Reads: half-wave lk groups at {0,16}(+8kb) / {8,24}(+8kb) -> each 32-lane
//    phase tiles all 32 banks. Writes: g-groups spaced 8, sr spans 8 -> tiled.
//    Zero bank conflicts.
//  - double-buffered LDS, ONE barrier per k-tile; next-tile global loads
//    issued before the MFMA section (latency hidden under MFMA).
// MFMA sequence per accumulator identical to v2/v3 (absmax 0 preserved).
// ---------------------------------------------------------------------------
#define GBM 128
#define GBN 128
#define GBK 16
#define ABUFSZ 2320   // AIDX(15,127)+1 = 2320
__device__ __forceinline__ int AIDX(int k, int r) {
    return k * 136 + ((k >> 2) * 40) + ((k & 3) * 8) + (((k >> 1) & 1) * 8) + r;
}
__global__ __launch_bounds__(512, 4) void k_gemm_mfma(const float* __restrict__ x,
                                                      const float* __restrict__ W1,
                                                      const float* __restrict__ b1,
                                                      double* __restrict__ m1out,
                                                      const int* __restrict__ flag) {
#if defined(HAVE_MFMA64)
    int fm = flag[0];
    if (fm < 1 || fm > 4) return;
    __shared__ float As[2][ABUFSZ];
    __shared__ float Bs[2][ABUFSZ];

    int tid = threadIdx.x;
    int m0 = blockIdx.x * GBM;
    int n0 = blockIdx.y * GBN;
    int w = tid >> 6, lane = tid & 63;
    int wr = w >> 2;        // 0..1 : 64-row half
    int wc = w & 3;         // 0..3 : 32-col quarter
    int lr = lane & 15, lk = lane >> 4;
    int srow = tid >> 2;           // 0..127
    int g    = tid & 3;
    int skq  = g * 4;
    // write offsets for the 4 rows this thread stages (row = skq+q, col = srow)
    int woff0 = AIDX(skq + 0, srow);
    int woff1 = AIDX(skq + 1, srow);
    int woff2 = AIDX(skq + 2, srow);
    int woff3 = AIDX(skq + 3, srow);

    d4 acc[4][2];
#pragma unroll
    for (int i = 0; i < 4; ++i)
#pragma unroll
        for (int j = 0; j < 2; ++j) acc[i][j] = (d4){0.0, 0.0, 0.0, 0.0};

    // prologue: stage tile 0
    {
        float4 av = *(const float4*)&x [(size_t)(m0 + srow) * D_ + skq];
        float4 bv = *(const float4*)&W1[(size_t)(n0 + srow) * D_ + skq];
        As[0][woff0] = av.x; As[0][woff1] = av.y;
        As[0][woff2] = av.z; As[0][woff3] = av.w;
        Bs[0][woff0] = bv.x; Bs[0][woff1] = bv.y;
        Bs[0][woff2] = bv.z; Bs[0][woff3] = bv.w;
    }
    __syncthreads();

    int cur = 0;
    const int NT = D_ / GBK;           // 64
    for (int t = 0; t < NT; ++t) {
        float4 avn, bvn;
        bool more = (t + 1 < NT);
        if (more) {
            int k0 = (t + 1) * GBK;
            avn = *(const float4*)&x [(size_t)(m0 + srow) * D_ + k0 + skq];
            bvn = *(const float4*)&W1[(size_t)(n0 + srow) * D_ + k0 + skq];
        }
        const float* Ac = As[cur];
        const float* Bc = Bs[cur];
#pragma unroll
        for (int kb = 0; kb < 4; ++kb) {
            int abase = AIDX(kb * 4 + lk, wr * 64 + lr);
            int bbase = AIDX(kb * 4 + lk, wc * 32 + lr);
            double a[4], bfr[2];
#pragma unroll
            for (int i = 0; i < 4; ++i)
                a[i] = (double)Ac[abase + 16 * i];
#pragma unroll
            for (int j = 0; j < 2; ++j)
                bfr[j] = (double)Bc[bbase + 16 * j];
#pragma unroll
            for (int i = 0; i < 4; ++i)
#pragma unroll
                for (int j = 0; j < 2; ++j)
                    acc[i][j] = MFMA64(a[i], bfr[j], acc[i][j]);
        }
        if (more) {
            float* An = As[cur ^ 1];
            float* Bn = Bs[cur ^ 1];
            An[woff0] = avn.x; An[woff1] = avn.y;
            An[woff2] = avn.z; An[woff3] = avn.w;
            Bn[woff0] = bvn.x; Bn[woff1] = bvn.y;
            Bn[woff2] = bvn.z; Bn[woff3] = bvn.w;
        }
        __syncthreads();
        cur ^= 1;
    }

    // epilogue: D-mapping selected by fm
#pragma unroll
    for (int j = 0; j < 2; ++j)
#pragma unroll
        for (int i = 0; i < 4; ++i)
#pragma unroll
            for (int r = 0; r < 4; ++r) {
                int rin = (fm == 1) ? (4 * lk + r) : (fm == 2) ? lr
                        : (fm == 3) ? (lk + 4 * r) : lr;
                int cin = (fm == 1) ? lr : (fm == 2) ? (4 * lk + r)
                        : (fm == 3) ? lr : (lk + 4 * r);
                int row = m0 + wr * 64 + 16 * i + rin;
                int col = n0 + wc * 32 + 16 * j + cin;
                m1out[(size_t)row * H1_ + col] = acc[i][j][r] + (double)b1[col];
            }
#else
    (void)x; (void)W1; (void)b1; (void)m1out; (void)flag;
#endif
}

// ---------------------------------------------------------------------------
// Fallback VALU f64 GEMM (proven). Runs iff flag not in {1..4}.
// ---------------------------------------------------------------------------
#define BM 128
#define BN 128
#define BK 8
__global__ __launch_bounds__(256) void k_gemm1(const float* __restrict__ x,
                                               const float* __restrict__ W1,
                                               const float* __restrict__ b1,
                                               double* __restrict__ m1out,
                                               const int* __restrict__ flag) {
    int fm = flag[0];
    if (fm >= 1 && fm <= 4) return;
    __shared__ double As[BK][BM + 4];
    __shared__ double Bs[BK][BN + 4];

    int tid = threadIdx.x;
    int m0 = blockIdx.x * BM;
    int n0 = blockIdx.y * BN;
    int tx = tid & 15;
    int ty = tid >> 4;
    int lr = tid >> 1;
    int lk = (tid & 1) * 4;

    double acc[8][8] = {};

    for (int k0 = 0; k0 < D_; k0 += BK) {
        float4 av = *(const float4*)&x [(size_t)(m0 + lr) * D_ + k0 + lk];
        float4 bv = *(const float4*)&W1[(size_t)(n0 + lr) * D_ + k0 + lk];
        __syncthreads();
        As[lk + 0][lr] = (double)av.x;
        As[lk + 1][lr] = (double)av.y;
        As[lk + 2][lr] = (double)av.z;
        As[lk + 3][lr] = (double)av.w;
        Bs[lk + 0][lr] = (double)bv.x;
        Bs[lk + 1][lr] = (double)bv.y;
        Bs[lk + 2][lr] = (double)bv.z;
        Bs[lk + 3][lr] = (double)bv.w;
        __syncthreads();
#pragma unroll
        for (int kk = 0; kk < BK; ++kk) {
            double a[8], b[8];
#pragma unroll
            for (int i = 0; i < 8; ++i) a[i] = As[kk][tx + 16 * i];
#pragma unroll
            for (int j = 0; j < 8; ++j) b[j] = Bs[kk][ty + 16 * j];
#pragma unroll
            for (int i = 0; i < 8; ++i)
#pragma unroll
                for (int j = 0; j < 8; ++j)
                    acc[i][j] += a[i] * b[j];
        }
    }
#pragma unroll
    for (int j = 0; j < 8; ++j) {
        double bj = (double)b1[n0 + ty + 16 * j];
#pragma unroll
        for (int i = 0; i < 8; ++i) {
            m1out[(size_t)(m0 + tx + 16 * i) * H1_ + (n0 + ty + 16 * j)] =
                acc[i][j] + bj;
        }
    }
}

// ---------------------------------------------------------------------------
// Persistent per-sample SNN v4 (unchanged from R7, ~135 µs).
// ---------------------------------------------------------------------------
__global__ __launch_bounds__(256) void k_snn(const double* __restrict__ m1_0,
                                             const float* __restrict__ b1,
                                             const float* __restrict__ W1T,
                                             const float* __restrict__ W2T,
                                             const float* __restrict__ b2,
                                             const float* __restrict__ Wo,
                                             const float* __restrict__ bo,
                                             const int* __restrict__ nsteps_p,
                                             float* __restrict__ out) {
    __shared__ __align__(16) double pjbuf[H2_];      // 8 KB; aliased as l1idx
    __shared__ __align__(16) int l2idx[H2_];         // 4 KB
    __shared__ unsigned long long s1by[32];          // 256 B
    __shared__ unsigned long long s2nb[32];          // 256 B
    __shared__ int ncnt[2];
    __shared__ int anyb1[4], anyb2[4];

    int* l1idx = (int*)pjbuf;

    int b = blockIdx.x;
    int tid = threadIdx.x;
    int lane = tid & 63;
    int wv = tid >> 6;
    int T = nsteps_p[0];

    double m1r[8], m2r[4];
    float b1f[8], b2f[4];
    int cnt[4];

    const double* m1p = m1_0 + (size_t)b * H1_ + 8 * tid;
    {
        double2 v0 = *(const double2*)(m1p + 0);
        double2 v1 = *(const double2*)(m1p + 2);
        double2 v2 = *(const double2*)(m1p + 4);
        double2 v3 = *(const double2*)(m1p + 6);
        m1r[0] = v0.x; m1r[1] = v0.y; m1r[2] = v1.x; m1r[3] = v1.y;
        m1r[4] = v2.x; m1r[5] = v2.y; m1r[6] = v3.x; m1r[7] = v3.y;
    }
    {
        float4 f0 = *(const float4*)(b1 + 8 * tid);
        float4 f1 = *(const float4*)(b1 + 8 * tid + 4);
        b1f[0] = f0.x; b1f[1] = f0.y; b1f[2] = f0.z; b1f[3] = f0.w;
        b1f[4] = f1.x; b1f[5] = f1.y; b1f[6] = f1.z; b1f[7] = f1.w;
        float4 f2 = *(const float4*)(b2 + 4 * tid);
        b2f[0] = f2.x; b2f[1] = f2.y; b2f[2] = f2.z; b2f[3] = f2.w;
    }
#pragma unroll
    for (int q = 0; q < 4; ++q) { m2r[q] = 0.0; cnt[q] = 0; }

    int anyS2 = 0;

#define ACC2(v) { m2r[0] += (double)(v).x; m2r[1] += (double)(v).y; \
                  m2r[2] += (double)(v).z; m2r[3] += (double)(v).w; }

    for (int t = 0; t < T; ++t) {
        if (t > 0) {
#pragma unroll
            for (int q = 0; q < 8; ++q)
                m1r[q] = 0.9 * m1r[q] - (m1r[q] > 1.0 ? 1.0 : 0.0) + (double)b1f[q];
            if (anyS2) {
                int n2 = ncnt[1];
                const char* Wc = (const char*)W1T;
                size_t toff = (size_t)tid << 5;
                for (int k2 = 0; k2 < n2; ++k2) {
                    const float4* c4 = (const float4*)(Wc + l2idx[k2] + toff);
                    float4 va = c4[0];
                    float4 vb = c4[1];
                    m1r[0] += (double)va.x; m1r[1] += (double)va.y;
                    m1r[2] += (double)va.z; m1r[3] += (double)va.w;
                    m1r[4] += (double)vb.x; m1r[5] += (double)vb.y;
                    m1r[6] += (double)vb.z; m1r[7] += (double)vb.w;
                }
            }
        }
        unsigned bflag = 0;
#pragma unroll
        for (int q = 0; q < 8; ++q) bflag |= (m1r[q] > 1.0 ? 1u : 0u) << q;
        ((unsigned char*)s1by)[tid] = (unsigned char)bflag;
        {
            int wa = __any((int)bflag);
            if (lane == 0) anyb1[wv] = wa;
        }
#pragma unroll
        for (int q = 0; q < 4; ++q)
            m2r[q] = 0.9 * m2r[q] - (m2r[q] > 1.0 ? 1.0 : 0.0) + (double)b2f[q];
        {
            unsigned nib = 0;
#pragma unroll
            for (int q = 0; q < 4; ++q) nib |= (m2r[q] > 1.0 ? 1u : 0u) << q;
            ((unsigned char*)s2nb)[tid] = (unsigned char)nib;
            int wa = __any((int)nib);
            if (lane == 0) anyb2[wv] = wa;
        }
        __syncthreads();                                   // A
        int any1 = anyb1[0] | anyb1[1] | anyb1[2] | anyb1[3];
        if (any1) {
            if (tid < 64) {
                unsigned long long bits = (tid < 32) ? s1by[tid] : 0ULL;
                int pc = __popcll(bits);
                int sc = pc;
#pragma unroll
                for (int d = 1; d < 64; d <<= 1) {
                    int o = __shfl_up(sc, d);
                    if (tid >= d) sc += o;
                }
                if (tid == 63) ncnt[0] = sc;
                int off = sc - pc;
                int base = tid << 6;
                while (bits) {
                    l1idx[off++] = (base + __builtin_ctzll(bits)) << 12;
                    bits &= bits - 1;
                }
            }
            __syncthreads();                               // B
            {
                int n1 = ncnt[0];
                const char* Wc = (const char*)W2T;
                size_t toff = (size_t)tid << 4;
                int k = 0;
                for (; k + 8 <= n1; k += 8) {
                    int4 oa = *(const int4*)&l1idx[k];
                    int4 ob = *(const int4*)&l1idx[k + 4];
                    float4 v0 = *(const float4*)(Wc + oa.x + toff);
                    float4 v1 = *(const float4*)(Wc + oa.y + toff);
                    float4 v2 = *(const float4*)(Wc + oa.z + toff);
                    float4 v3 = *(const float4*)(Wc + oa.w + toff);
                    float4 v4 = *(const float4*)(Wc + ob.x + toff);
                    float4 v5 = *(const float4*)(Wc + ob.y + toff);
                    float4 v6 = *(const float4*)(Wc + ob.z + toff);
                    float4 v7 = *(const float4*)(Wc + ob.w + toff);
                    ACC2(v0); ACC2(v1); ACC2(v2); ACC2(v3);
                    ACC2(v4); ACC2(v5); ACC2(v6); ACC2(v7);
                }
                for (; k < n1; ++k) {
                    float4 v = *(const float4*)(Wc + l1idx[k] + toff);
                    ACC2(v);
                }
            }
            {
                unsigned nib = 0;
#pragma unroll
                for (int q = 0; q < 4; ++q) nib |= (m2r[q] > 1.0 ? 1u : 0u) << q;
                ((unsigned char*)s2nb)[tid] = (unsigned char)nib;
                int wa = __any((int)nib);
                if (lane == 0) anyb2[wv] = wa;
            }
            __syncthreads();                               // C
        }
        anyS2 = anyb2[0] | anyb2[1] | anyb2[2] | anyb2[3];
#pragma unroll
        for (int q = 0; q < 4; ++q) cnt[q] += (m2r[q] > 1.0) ? 1 : 0;
        if (anyS2) {
            if (tid < 64) {
                unsigned long long wbits = 0ULL;
                if (tid < 16) {
                    unsigned long long w0 = s2nb[2 * tid];
                    unsigned long long w1 = s2nb[2 * tid + 1];
                    w0 &= 0x0F0F0F0F0F0F0F0FULL;
                    w0 = (w0 | (w0 >> 4)) & 0x00FF00FF00FF00FFULL;
                    w0 = (w0 | (w0 >> 8)) & 0x0000FFFF0000FFFFULL;
                    w0 = (w0 | (w0 >> 16)) & 0x00000000FFFFFFFFULL;
                    w1 &= 0x0F0F0F0F0F0F0F0FULL;
                    w1 = (w1 | (w1 >> 4)) & 0x00FF00FF00FF00FFULL;
                    w1 = (w1 | (w1 >> 8)) & 0x0000FFFF0000FFFFULL;
                    w1 = (w1 | (w1 >> 16)) & 0x00000000FFFFFFFFULL;
                    wbits = w0 | (w1 << 32);
                }
                int pc = __popcll(wbits);
                int sc = pc;
#pragma unroll
                for (int d = 1; d < 64; d <<= 1) {
                    int o = __shfl_up(sc, d);
                    if (tid >= d) sc += o;
                }
                if (tid == 63) ncnt[1] = sc;
                int off = sc - pc;
                int base = tid << 6;
                while (wbits) {
                    l2idx[off++] = (base + __builtin_ctzll(wbits)) << 13;
                    wbits &= wbits - 1;
                }
            }
            __syncthreads();                               // D
        }
    }
#undef ACC2

    // ---- sparse epilogue ----
    __syncthreads();
#pragma unroll
    for (int q = 0; q < 4; ++q)
        pjbuf[4 * tid + q] = (double)cnt[q] / (double)T;
    {
        unsigned nib = 0;
#pragma unroll
        for (int q = 0; q < 4; ++q) nib |= (cnt[q] > 0 ? 1u : 0u) << q;
        ((unsigned char*)s2nb)[tid] = (unsigned char)nib;
    }
    __syncthreads();
    if (tid < 64) {
        unsigned long long wbits = 0ULL;
        if (tid < 16) {
            unsigned long long w0 = s2nb[2 * tid];
            unsigned long long w1 = s2nb[2 * tid + 1];
            w0 &= 0x0F0F0F0F0F0F0F0FULL;
            w0 = (w0 | (w0 >> 4)) & 0x00FF00FF00FF00FFULL;
            w0 = (w0 | (w0 >> 8)) & 0x0000FFFF0000FFFFULL;
            w0 = (w0 | (w0 >> 16)) & 0x00000000FFFFFFFFULL;
            w1 &= 0x0F0F0F0F0F0F0F0FULL;
            w1 = (w1 | (w1 >> 4)) & 0x00FF00FF00FF00FFULL;
            w1 = (w1 | (w1 >> 8)) & 0x0000FFFF0000FFFFULL;
            w1 = (w1 | (w1 >> 16)) & 0x00000000FFFFFFFFULL;
            wbits = w0 | (w1 << 32);
        }
        int pc = __popcll(wbits);
        int sc = pc;
#pragma unroll
        for (int d = 1; d < 64; d <<= 1) {
            int o = __shfl_up(sc, d);
            if (tid >= d) sc += o;
        }
        if (tid == 63) ncnt[1] = sc;
        int off = sc - pc;
        int base = tid << 6;
        while (wbits) {
            l2idx[off++] = base + __builtin_ctzll(wbits);
            wbits &= wbits - 1;
        }
    }
    __syncthreads();
    if (tid < C_) {
        int c = tid;
        int na = ncnt[1];
        const float* worow = &Wo[(size_t)c * H2_];
        double acc = 0.0;
        for (int k = 0; k < na; ++k) {
            int j = l2idx[k];
            acc += pjbuf[j] * (double)worow[j];
        }
        out[(size_t)b * C_ + c] = (float)(acc + (double)bo[c]);
    }
}

// ---------------------------------------------------------------------------
extern "C" void kernel_launch(void* const* d_in, const int* in_sizes, int n_in,
                              void* d_out, int out_size, void* d_ws, size_t ws_size,
                              hipStream_t stream) {
    const float* x  = (const float*)d_in[0];   // [4096,1024]
    const float* W1 = (const float*)d_in[1];   // [2048,1024]
    const float* b1 = (const float*)d_in[2];   // [2048]
    const float* W2 = (const float*)d_in[3];   // [1024,2048]
    const float* b2 = (const float*)d_in[4];   // [1024]
    const float* Wo = (const float*)d_in[5];   // [64,1024]
    const float* bo = (const float*)d_in[6];   // [64]
    const int* nst  = (const int*)d_in[7];     // [1] = 20
    float* out = (float*)d_out;

    size_t off_m1   = 0;                                   // f64 [4096][2048]
    size_t off_w1t  = off_m1 + (size_t)B_ * H1_ * 8;
    size_t off_w2t  = off_w1t + (size_t)D_ * H1_ * 4;
    size_t off_flag = off_w2t + (size_t)H1_ * H2_ * 4;
    size_t need     = off_flag + 64;
    if (ws_size < need) return;

    double* m1ws = (double*)((char*)d_ws + off_m1);
    float*  W1T  = (float*)((char*)d_ws + off_w1t);
    float*  W2T  = (float*)((char*)d_ws + off_w2t);
    int*    flag = (int*)((char*)d_ws + off_flag);

    k_probe<<<1, 64, 0, stream>>>(flag);

    k_transpose<<<dim3(D_ / 32, H1_ / 32), dim3(32, 8), 0, stream>>>(W1, W1T, H1_, D_);
    k_transpose<<<dim3(H1_ / 32, H2_ / 32), dim3(32, 8), 0, stream>>>(W2, W2T, H2_, H1_);

    k_gemm_mfma<<<dim3(B_ / GBM, H1_ / GBN), 512, 0, stream>>>(x, W1, b1, m1ws, flag);
    k_gemm1<<<dim3(B_ / BM, H1_ / BN), 256, 0, stream>>>(x, W1, b1, m1ws, flag);

    k_snn<<<B_, 256, 0, stream>>>(m1ws, b1, W1T, W2T, b2, Wo, bo, nst, out);
}

// Round 10
// 437.216 us; speedup vs baseline: 1.0215x; 1.0215x over previous
//
#include <hip/hip_runtime.h>
#include <hip/hip_bf16.h>

// Sizes (fixed by the reference): B=4096, D=1024, H1=2048, H2=1024, C=64, T=20
#define B_   4096
#define D_   1024
#define H1_  2048
#define H2_  1024
#define C_   64

typedef double d4 __attribute__((ext_vector_type(4)));

#if defined(__has_builtin)
#  if __has_builtin(__builtin_amdgcn_mfma_f64_16x16x4f64)
#    define MFMA64(A, B, C) __builtin_amdgcn_mfma_f64_16x16x4f64((A), (B), (C), 0, 0, 0)
#    define HAVE_MFMA64 1
#  elif __has_builtin(__builtin_amdgcn_mfma_f64_16x16x4_f64)
#    define MFMA64(A, B, C) __builtin_amdgcn_mfma_f64_16x16x4_f64((A), (B), (C), 0, 0, 0)
#    define HAVE_MFMA64 1
#  endif
#endif

// ---------------------------------------------------------------------------
// Probe: discover v_mfma_f64_16x16x4 D-fragment layout at runtime.
// ---------------------------------------------------------------------------
__global__ void k_probe(int* flag) {
#if defined(HAVE_MFMA64)
    int lane = threadIdx.x & 63;
    int lr = lane & 15, lk = lane >> 4;
    double a  = (double)(5 * lr + 3 * lk + 1);    // A[r][k] = 5r+3k+1
    double bb = (double)(11 * lk + 2 * lr + 2);   // B[k][c] = 11k+2c+2
    d4 c = {0.0, 0.0, 0.0, 0.0};
    c = MFMA64(a, bb, c);
    int okm[4] = {1, 1, 1, 1};
#pragma unroll
    for (int j = 0; j < 4; ++j) {
        double e1 = 0, e2 = 0, e3 = 0, e4 = 0;
        for (int k = 0; k < 4; ++k) {
            e1 += (double)(5 * (4 * lk + j) + 3 * k + 1) * (double)(11 * k + 2 * lr + 2);
            e2 += (double)(5 * lr + 3 * k + 1) * (double)(11 * k + 2 * (4 * lk + j) + 2);
            e3 += (double)(5 * (lk + 4 * j) + 3 * k + 1) * (double)(11 * k + 2 * lr + 2);
            e4 += (double)(5 * lr + 3 * k + 1) * (double)(11 * k + 2 * (lk + 4 * j) + 2);
        }
        if (c[j] != e1) okm[0] = 0;
        if (c[j] != e2) okm[1] = 0;
        if (c[j] != e3) okm[2] = 0;
        if (c[j] != e4) okm[3] = 0;
    }
    int f = 0;
    for (int m = 3; m >= 0; --m) {
        unsigned long long all = __ballot(okm[m] != 0);
        if (all == ~0ULL) f = m + 1;
    }
    if (lane == 0) flag[0] = f;
#else
    if ((threadIdx.x & 63) == 0) flag[0] = 0;
#endif
}

// ---------------------------------------------------------------------------
// Transpose: out[c][r] = in[r][c]   (f32, 32x32 LDS tiles)
// ---------------------------------------------------------------------------
__global__ __launch_bounds__(256) void k_transpose(const float* __restrict__ in,
                                                   float* __restrict__ out,
                                                   int R, int C) {
    __shared__ float t[32][33];
    int c0 = blockIdx.x * 32;
    int r0 = blockIdx.y * 32;
    int lx = threadIdx.x;
    int ly = threadIdx.y;
#pragma unroll
    for (int q = 0; q < 4; ++q) {
        int rr = ly + 8 * q;
        t[rr][lx] = in[(size_t)(r0 + rr) * C + (c0 + lx)];
    }
    __syncthreads();
#pragma unroll
    for (int q = 0; q < 4; ++q) {
        int cc = ly + 8 * q;
        out[(size_t)(c0 + cc) * R + (r0 + lx)] = t[lx][cc];
    }
}

// ---------------------------------------------------------------------------
// f64 MFMA GEMM v5: 128x128 tile, GBK=32, 512 thr, wave-tile 64x32.
// Single-buffer (2 barriers per k-tile, 32 tiles = half of v3's windows).
// LDS stores f64 (convert once at staging write; (double)(float) exact).
// Pad: AIDX64(k,r) = 136k + 8*(k>>2) + r (doubles).
//   writes: 32-lane phase hits each of 16 bank-pairs exactly 2x (minimum).
//   reads:  lr spans all 16 pairs per lk group (minimum). Zero conflicts.
// k-order per accumulator identical to v2..v4 (absmax 0 preserved).
// ---------------------------------------------------------------------------
#define GBM 128
#define GBN 128
#define GBK 32
#define ABUFSZ64 4400   // AIDX64(31,127)+1 = 4400 doubles = 35.2 KB
__device__ __forceinline__ int AIDX64(int k, int r) {
    return k * 136 + ((k >> 2) << 3) + r;
}
__global__ __launch_bounds__(512, 4) void k_gemm_mfma(const float* __restrict__ x,
                                                      const float* __restrict__ W1,
                                                      const float* __restrict__ b1,
                                                      double* __restrict__ m1out,
                                                      const int* __restrict__ flag) {
#if defined(HAVE_MFMA64)
    int fm = flag[0];
    if (fm < 1 || fm > 4) return;
    __shared__ double As[ABUFSZ64];   // 35.2 KB
    __shared__ double Bs[ABUFSZ64];   // 35.2 KB (70.4 KB total, 2 blocks/CU)

    int tid = threadIdx.x;
    int m0 = blockIdx.x * GBM;
    int n0 = blockIdx.y * GBN;
    int w = tid >> 6, lane = tid & 63;
    int wr = w >> 2;        // 0..1 : 64-row half
    int wc = w & 3;         // 0..3 : 32-col quarter
    int lr = lane & 15, lk = lane >> 4;
    int srow = tid >> 2;           // 0..127
    int g    = tid & 3;
    int skq  = g * 4;              // k offset 0,4,8,12 (plus +16 second group)
    int woff = AIDX64(skq, srow);  // consecutive q adds 136; +16 k adds 2208

    const float* xrow = x  + (size_t)(m0 + srow) * D_;
    const float* wrow = W1 + (size_t)(n0 + srow) * D_;

    d4 acc[4][2];
#pragma unroll
    for (int i = 0; i < 4; ++i)
#pragma unroll
        for (int j = 0; j < 2; ++j) acc[i][j] = (d4){0.0, 0.0, 0.0, 0.0};

    for (int k0 = 0; k0 < D_; k0 += GBK) {
        float4 a0 = *(const float4*)&xrow[k0 + skq];
        float4 a1 = *(const float4*)&xrow[k0 + skq + 16];
        float4 g0 = *(const float4*)&wrow[k0 + skq];
        float4 g1 = *(const float4*)&wrow[k0 + skq + 16];
        __syncthreads();   // all fragment reads of previous tile complete
        As[woff +    0] = (double)a0.x;
        As[woff +  136] = (double)a0.y;
        As[woff +  272] = (double)a0.z;
        As[woff +  408] = (double)a0.w;
        As[woff + 2208] = (double)a1.x;
        As[woff + 2344] = (double)a1.y;
        As[woff + 2480] = (double)a1.z;
        As[woff + 2616] = (double)a1.w;
        Bs[woff +    0] = (double)g0.x;
        Bs[woff +  136] = (double)g0.y;
        Bs[woff +  272] = (double)g0.z;
        Bs[woff +  408] = (double)g0.w;
        Bs[woff + 2208] = (double)g1.x;
        Bs[woff + 2344] = (double)g1.y;
        Bs[woff + 2480] = (double)g1.z;
        Bs[woff + 2616] = (double)g1.w;
        __syncthreads();   // tile staged
#pragma unroll
        for (int kb = 0; kb < 8; ++kb) {
            int abase = AIDX64(kb * 4 + lk, wr * 64 + lr);
            int bbase = AIDX64(kb * 4 + lk, wc * 32 + lr);
            double a[4], bfr[2];
#pragma unroll
            for (int i = 0; i < 4; ++i)
                a[i] = As[abase + 16 * i];
#pragma unroll
            for (int j = 0; j < 2; ++j)
                bfr[j] = Bs[bbase + 16 * j];
#pragma unroll
            for (int i = 0; i < 4; ++i)
#pragma unroll
                for (int j = 0; j < 2; ++j)
                    acc[i][j] = MFMA64(a[i], bfr[j], acc[i][j]);
        }
    }

    // epilogue: D-mapping selected by fm
#pragma unroll
    for (int j = 0; j < 2; ++j)
#pragma unroll
        for (int i = 0; i < 4; ++i)
#pragma unroll
            for (int r = 0; r < 4; ++r) {
                int rin = (fm == 1) ? (4 * lk + r) : (fm == 2) ? lr
                        : (fm == 3) ? (lk + 4 * r) : lr;
                int cin = (fm == 1) ? lr : (fm == 2) ? (4 * lk + r)
                        : (fm == 3) ? lr : (lk + 4 * r);
                int row = m0 + wr * 64 + 16 * i + rin;
                int col = n0 + wc * 32 + 16 * j + cin;
                m1out[(size_t)row * H1_ + col] = acc[i][j][r] + (double)b1[col];
            }
#else
    (void)x; (void)W1; (void)b1; (void)m1out; (void)flag;
#endif
}

// ---------------------------------------------------------------------------
// Fallback VALU f64 GEMM (proven). Runs iff flag not in {1..4}.
// ---------------------------------------------------------------------------
#define BM 128
#define BN 128
#define BK 8
__global__ __launch_bounds__(256) void k_gemm1(const float* __restrict__ x,
                                               const float* __restrict__ W1,
                                               const float* __restrict__ b1,
                                               double* __restrict__ m1out,
                                               const int* __restrict__ flag) {
    int fm = flag[0];
    if (fm >= 1 && fm <= 4) return;
    __shared__ double As[BK][BM + 4];
    __shared__ double Bs[BK][BN + 4];

    int tid = threadIdx.x;
    int m0 = blockIdx.x * BM;
    int n0 = blockIdx.y * BN;
    int tx = tid & 15;
    int ty = tid >> 4;
    int lr = tid >> 1;
    int lk = (tid & 1) * 4;

    double acc[8][8] = {};

    for (int k0 = 0; k0 < D_; k0 += BK) {
        float4 av = *(const float4*)&x [(size_t)(m0 + lr) * D_ + k0 + lk];
        float4 bv = *(const float4*)&W1[(size_t)(n0 + lr) * D_ + k0 + lk];
        __syncthreads();
        As[lk + 0][lr] = (double)av.x;
        As[lk + 1][lr] = (double)av.y;
        As[lk + 2][lr] = (double)av.z;
        As[lk + 3][lr] = (double)av.w;
        Bs[lk + 0][lr] = (double)bv.x;
        Bs[lk + 1][lr] = (double)bv.y;
        Bs[lk + 2][lr] = (double)bv.z;
        Bs[lk + 3][lr] = (double)bv.w;
        __syncthreads();
#pragma unroll
        for (int kk = 0; kk < BK; ++kk) {
            double a[8], b[8];
#pragma unroll
            for (int i = 0; i < 8; ++i) a[i] = As[kk][tx + 16 * i];
#pragma unroll
            for (int j = 0; j < 8; ++j) b[j] = Bs[kk][ty + 16 * j];
#pragma unroll
            for (int i = 0; i < 8; ++i)
#pragma unroll
                for (int j = 0; j < 8; ++j)
                    acc[i][j] += a[i] * b[j];
        }
    }
#pragma unroll
    for (int j = 0; j < 8; ++j) {
        double bj = (double)b1[n0 + ty + 16 * j];
#pragma unroll
        for (int i = 0; i < 8; ++i) {
            m1out[(size_t)(m0 + tx + 16 * i) * H1_ + (n0 + ty + 16 * j)] =
                acc[i][j] + bj;
        }
    }
}

// ---------------------------------------------------------------------------
// Persistent per-sample SNN v4 (unchanged from R7, ~135 µs).
// ---------------------------------------------------------------------------
__global__ __launch_bounds__(256) void k_snn(const double* __restrict__ m1_0,
                                             const float* __restrict__ b1,
                                             const float* __restrict__ W1T,
                                             const float* __restrict__ W2T,
                                             const float* __restrict__ b2,
                                             const float* __restrict__ Wo,
                                             const float* __restrict__ bo,
                                             const int* __restrict__ nsteps_p,
                                             float* __restrict__ out) {
    __shared__ __align__(16) double pjbuf[H2_];      // 8 KB; aliased as l1idx
    __shared__ __align__(16) int l2idx[H2_];         // 4 KB
    __shared__ unsigned long long s1by[32];          // 256 B
    __shared__ unsigned long long s2nb[32];          // 256 B
    __shared__ int ncnt[2];
    __shared__ int anyb1[4], anyb2[4];

    int* l1idx = (int*)pjbuf;

    int b = blockIdx.x;
    int tid = threadIdx.x;
    int lane = tid & 63;
    int wv = tid >> 6;
    int T = nsteps_p[0];

    double m1r[8], m2r[4];
    float b1f[8], b2f[4];
    int cnt[4];

    const double* m1p = m1_0 + (size_t)b * H1_ + 8 * tid;
    {
        double2 v0 = *(const double2*)(m1p + 0);
        double2 v1 = *(const double2*)(m1p + 2);
        double2 v2 = *(const double2*)(m1p + 4);
        double2 v3 = *(const double2*)(m1p + 6);
        m1r[0] = v0.x; m1r[1] = v0.y; m1r[2] = v1.x; m1r[3] = v1.y;
        m1r[4] = v2.x; m1r[5] = v2.y; m1r[6] = v3.x; m1r[7] = v3.y;
    }
    {
        float4 f0 = *(const float4*)(b1 + 8 * tid);
        float4 f1 = *(const float4*)(b1 + 8 * tid + 4);
        b1f[0] = f0.x; b1f[1] = f0.y; b1f[2] = f0.z; b1f[3] = f0.w;
        b1f[4] = f1.x; b1f[5] = f1.y; b1f[6] = f1.z; b1f[7] = f1.w;
        float4 f2 = *(const float4*)(b2 + 4 * tid);
        b2f[0] = f2.x; b2f[1] = f2.y; b2f[2] = f2.z; b2f[3] = f2.w;
    }
#pragma unroll
    for (int q = 0; q < 4; ++q) { m2r[q] = 0.0; cnt[q] = 0; }

    int anyS2 = 0;

#define ACC2(v) { m2r[0] += (double)(v).x; m2r[1] += (double)(v).y; \
                  m2r[2] += (double)(v).z; m2r[3] += (double)(v).w; }

    for (int t = 0; t < T; ++t) {
        if (t > 0) {
#pragma unroll
            for (int q = 0; q < 8; ++q)
                m1r[q] = 0.9 * m1r[q] - (m1r[q] > 1.0 ? 1.0 : 0.0) + (double)b1f[q];
            if (anyS2) {
                int n2 = ncnt[1];
                const char* Wc = (const char*)W1T;
                size_t toff = (size_t)tid << 5;
                for (int k2 = 0; k2 < n2; ++k2) {
                    const float4* c4 = (const float4*)(Wc + l2idx[k2] + toff);
                    float4 va = c4[0];
                    float4 vb = c4[1];
                    m1r[0] += (double)va.x; m1r[1] += (double)va.y;
                    m1r[2] += (double)va.z; m1r[3] += (double)va.w;
                    m1r[4] += (double)vb.x; m1r[5] += (double)vb.y;
                    m1r[6] += (double)vb.z; m1r[7] += (double)vb.w;
                }
            }
        }
        unsigned bflag = 0;
#pragma unroll
        for (int q = 0; q < 8; ++q) bflag |= (m1r[q] > 1.0 ? 1u : 0u) << q;
        ((unsigned char*)s1by)[tid] = (unsigned char)bflag;
        {
            int wa = __any((int)bflag);
            if (lane == 0) anyb1[wv] = wa;
        }
#pragma unroll
        for (int q = 0; q < 4; ++q)
            m2r[q] = 0.9 * m2r[q] - (m2r[q] > 1.0 ? 1.0 : 0.0) + (double)b2f[q];
        {
            unsigned nib = 0;
#pragma unroll
            for (int q = 0; q < 4; ++q) nib |= (m2r[q] > 1.0 ? 1u : 0u) << q;
            ((unsigned char*)s2nb)[tid] = (unsigned char)nib;
            int wa = __any((int)nib);
            if (lane == 0) anyb2[wv] = wa;
        }
        __syncthreads();                                   // A
        int any1 = anyb1[0] | anyb1[1] | anyb1[2] | anyb1[3];
        if (any1) {
            if (tid < 64) {
                unsigned long long bits = (tid < 32) ? s1by[tid] : 0ULL;
                int pc = __popcll(bits);
                int sc = pc;
#pragma unroll
                for (int d = 1; d < 64; d <<= 1) {
                    int o = __shfl_up(sc, d);
                    if (tid >= d) sc += o;
                }
                if (tid == 63) ncnt[0] = sc;
                int off = sc - pc;
                int base = tid << 6;
                while (bits) {
                    l1idx[off++] = (base + __builtin_ctzll(bits)) << 12;
                    bits &= bits - 1;
                }
            }
            __syncthreads();                               // B
            {
                int n1 = ncnt[0];
                const char* Wc = (const char*)W2T;
                size_t toff = (size_t)tid << 4;
                int k = 0;
                for (; k + 8 <= n1; k += 8) {
                    int4 oa = *(const int4*)&l1idx[k];
                    int4 ob = *(const int4*)&l1idx[k + 4];
                    float4 v0 = *(const float4*)(Wc + oa.x + toff);
                    float4 v1 = *(const float4*)(Wc + oa.y + toff);
                    float4 v2 = *(const float4*)(Wc + oa.z + toff);
                    float4 v3 = *(const float4*)(Wc + oa.w + toff);
                    float4 v4 = *(const float4*)(Wc + ob.x + toff);
                    float4 v5 = *(const float4*)(Wc + ob.y + toff);
                    float4 v6 = *(const float4*)(Wc + ob.z + toff);
                    float4 v7 = *(const float4*)(Wc + ob.w + toff);
                    ACC2(v0); ACC2(v1); ACC2(v2); ACC2(v3);
                    ACC2(v4); ACC2(v5); ACC2(v6); ACC2(v7);
                }
                for (; k < n1; ++k) {
                    float4 v = *(const float4*)(Wc + l1idx[k] + toff);
                    ACC2(v);
                }
            }
            {
                unsigned nib = 0;
#pragma unroll
                for (int q = 0; q < 4; ++q) nib |= (m2r[q] > 1.0 ? 1u : 0u) << q;
                ((unsigned char*)s2nb)[tid] = (unsigned char)nib;
                int wa = __any((int)nib);
                if (lane == 0) anyb2[wv] = wa;
            }
            __syncthreads();                               // C
        }
        anyS2 = anyb2[0] | anyb2[1] | anyb2[2] | anyb2[3];
#pragma unroll
        for (int q = 0; q < 4; ++q) cnt[q] += (m2r[q] > 1.0) ? 1 : 0;
        if (anyS2) {
            if (tid < 64) {
                unsigned long long wbits = 0ULL;
                if (tid < 16) {
                    unsigned long long w0 = s2nb[2 * tid];
                    unsigned long long w1 = s2nb[2 * tid + 1];
                    w0 &= 0x0F0F0F0F0F0F0F0FULL;
                    w0 = (w0 | (w0 >> 4)) & 0x00FF00FF00FF00FFULL;
                    w0 = (w0 | (w0 >> 8)) & 0x0000FFFF0000FFFFULL;
                    w0 = (w0 | (w0 >> 16)) & 0x00000000FFFFFFFFULL;
                    w1 &= 0x0F0F0F0F0F0F0F0FULL;
                    w1 = (w1 | (w1 >> 4)) & 0x00FF00FF00FF00FFULL;
                    w1 = (w1 | (w1 >> 8)) & 0x0000FFFF0000FFFFULL;
                    w1 = (w1 | (w1 >> 16)) & 0x00000000FFFFFFFFULL;
                    wbits = w0 | (w1 << 32);
                }
                int pc = __popcll(wbits);
                int sc = pc;
#pragma unroll
                for (int d = 1; d < 64; d <<= 1) {
                    int o = __shfl_up(sc, d);
                    if (tid >= d) sc += o;
                }
                if (tid == 63) ncnt[1] = sc;
                int off = sc - pc;
                int base = tid << 6;
                while (wbits) {
                    l2idx[off++] = (base + __builtin_ctzll(wbits)) << 13;
                    wbits &= wbits - 1;
                }
            }
            __syncthreads();                               // D
        }
    }
#undef ACC2

    // ---- sparse epilogue ----
    __syncthreads();
#pragma unroll
    for (int q = 0; q < 4; ++q)
        pjbuf[4 * tid + q] = (double)cnt[q] / (double)T;
    {
        unsigned nib = 0;
#pragma unroll
        for (int q = 0; q < 4; ++q) nib |= (cnt[q] > 0 ? 1u : 0u) << q;
        ((unsigned char*)s2nb)[tid] = (unsigned char)nib;
    }
    __syncthreads();
    if (tid < 64) {
        unsigned long long wbits = 0ULL;
        if (tid < 16) {
            unsigned long long w0 = s2nb[2 * tid];
            unsigned long long w1 = s2nb[2 * tid + 1];
            w0 &= 0x0F0F0F0F0F0F0F0FULL;
            w0 = (w0 | (w0 >> 4)) & 0x00FF00FF00FF00FFULL;
            w0 = (w0 | (w0 >> 8)) & 0x0000FFFF0000FFFFULL;
            w0 = (w0 | (w0 >> 16)) & 0x00000000FFFFFFFFULL;
            w1 &= 0x0F0F0F0F0F0F0F0FULL;
            w1 = (w1 | (w1 >> 4)) & 0x00FF00FF00FF00FFULL;
            w1 = (w1 | (w1 >> 8)) & 0x0000FFFF0000FFFFULL;
            w1 = (w1 | (w1 >> 16)) & 0x00000000FFFFFFFFULL;
            wbits = w0 | (w1 << 32);
        }
        int pc = __popcll(wbits);
        int sc = pc;
#pragma unroll
        for (int d = 1; d < 64; d <<= 1) {
            int o = __shfl_up(sc, d);
            if (tid >= d) sc += o;
        }
        if (tid == 63) ncnt[1] = sc;
        int off = sc - pc;
        int base = tid << 6;
        while (wbits) {
            l2idx[off++] = base + __builtin_ctzll(wbits);
            wbits &= wbits - 1;
        }
    }
    __syncthreads();
    if (tid < C_) {
        int c = tid;
        int na = ncnt[1];
        const float* worow = &Wo[(size_t)c * H2_];
        double acc = 0.0;
        for (int k = 0; k < na; ++k) {
            int j = l2idx[k];
            acc += pjbuf[j] * (double)worow[j];
        }
        out[(size_t)b * C_ + c] = (float)(acc + (double)bo[c]);
    }
}

// ---------------------------------------------------------------------------
extern "C" void kernel_launch(void* const* d_in, const int* in_sizes, int n_in,
                              void* d_out, int out_size, void* d_ws, size_t ws_size,
                              hipStream_t stream) {
    const float* x  = (const float*)d_in[0];   // [4096,1024]
    const float* W1 = (const float*)d_in[1];   // [2048,1024]
    const float* b1 = (const float*)d_in[2];   // [2048]
    const float* W2 = (const float*)d_in[3];   // [1024,2048]
    const float* b2 = (const float*)d_in[4];   // [1024]
    const float* Wo = (const float*)d_in[5];   // [64,1024]
    const float* bo = (const float*)d_in[6];   // [64]
    const int* nst  = (const int*)d_in[7];     // [1] = 20
    float* out = (float*)d_out;

    size_t off_m1   = 0;                                   // f64 [4096][2048]
    size_t off_w1t  = off_m1 + (size_t)B_ * H1_ * 8;
    size_t off_w2t  = off_w1t + (size_t)D_ * H1_ * 4;
    size_t off_flag = off_w2t + (size_t)H1_ * H2_ * 4;
    size_t need     = off_flag + 64;
    if (ws_size < need) return;

    double* m1ws = (double*)((char*)d_ws + off_m1);
    float*  W1T  = (float*)((char*)d_ws + off_w1t);
    float*  W2T  = (float*)((char*)d_ws + off_w2t);
    int*    flag = (int*)((char*)d_ws + off_flag);

    k_probe<<<1, 64, 0, stream>>>(flag);

    k_transpose<<<dim3(D_ / 32, H1_ / 32), dim3(32, 8), 0, stream>>>(W1, W1T, H1_, D_);
    k_transpose<<<dim3(H1_ / 32, H2_ / 32), dim3(32, 8), 0, stream>>>(W2, W2T, H2_, H1_);

    k_gemm_mfma<<<dim3(B_ / GBM, H1_ / GBN), 512, 0, stream>>>(x, W1, b1, m1ws, flag);
    k_gemm1<<<dim3(B_ / BM, H1_ / BN), 256, 0, stream>>>(x, W1, b1, m1ws, flag);

    k_snn<<<B_, 256, 0, stream>>>(m1ws, b1, W1T, W2T, b2, Wo, bo, nst, out);
}